// Round 1
// baseline (696.214 us; speedup 1.0000x reference)
//
#include <hip/hip_runtime.h>
#include <cstdio>

// VQ nearest-codebook: stage-1 bf16 MFMA argmin (s = 0.5||c||^2 - x.c), flag
// near-ties (gap < TAU_S), exact refine for flagged, then gather rows.
// M=65536 queries, K=512, N=1024 codes. All shapes exact multiples of tiles.

typedef short short8 __attribute__((ext_vector_type(8)));
typedef float f32x4 __attribute__((ext_vector_type(4)));

#define KDIM 512
#define NCODES 1024
#define TAU_S 0.30f   // s-units (= d2/2). err-diff sigma ~0.05 -> ~6 sigma.

// ---- workspace layout (bytes) ----
#define WS_CBP  0                      // bf16 codebook, permuted [no][ki][kg][n][8]: 1 MB
#define WS_C2H  (1 << 20)              // float 0.5*||c||^2  [1024]
#define WS_C2D  (WS_C2H + 4096)       // double 0.5*||c||^2 [1024]
#define WS_IDX  (WS_C2D + 8192)      // int idx[65536]
#define WS_LIST (WS_IDX + 262144)     // int flagged[65536]
#define WS_CTR  (WS_LIST + 262144)    // int counter

__device__ __forceinline__ unsigned short f2bf(float f) {
  unsigned u = __builtin_bit_cast(unsigned, f);
  u += 0x7fffu + ((u >> 16) & 1u);    // RNE on bf16 boundary
  return (unsigned short)(u >> 16);
}

// ---------------- prep: codebook -> bf16 (permuted) + c2 (fp64) ----------------
__global__ __launch_bounds__(256) void vq_prep(const float* __restrict__ cb,
                                               unsigned short* __restrict__ cbp,
                                               float* __restrict__ c2h,
                                               double* __restrict__ c2d) {
  int lane = threadIdx.x & 63;
  int row = blockIdx.x * 4 + (threadIdx.x >> 6);      // 256 blocks * 4 rows
  const float4* src = (const float4*)(cb + (size_t)row * KDIM);
  float4 u = src[lane * 2], v = src[lane * 2 + 1];
  double p = (double)u.x * u.x + (double)u.y * u.y + (double)u.z * u.z + (double)u.w * u.w +
             (double)v.x * v.x + (double)v.y * v.y + (double)v.z * v.z + (double)v.w * v.w;
#pragma unroll
  for (int m = 1; m < 64; m <<= 1) p += __shfl_xor(p, m);
  if (lane == 0) { c2h[row] = (float)(0.5 * p); c2d[row] = 0.5 * p; }
  unsigned r0 = f2bf(u.x) | ((unsigned)f2bf(u.y) << 16);
  unsigned r1 = f2bf(u.z) | ((unsigned)f2bf(u.w) << 16);
  unsigned r2 = f2bf(v.x) | ((unsigned)f2bf(v.y) << 16);
  unsigned r3 = f2bf(v.z) | ((unsigned)f2bf(v.w) << 16);
  // lane = global k-group (8 elems). chunk = (nouter,kiter) of 16KB, inside: [kg][n][8]
  int kiter = lane >> 2, kgl = lane & 3, nouter = row >> 8, nloc = row & 255;
  size_t e = (((size_t)((nouter * 16 + kiter) * 4 + kgl)) * 256 + nloc) * 8;
  *(int4*)(cbp + e) = make_int4((int)r0, (int)r1, (int)r2, (int)r3);
}

// ---------------- main: bf16 MFMA GEMM + fused argmin ----------------
// grid 512 (M-tiles of 128), block 512 thr = 8 waves (2 m-waves x 4 n-waves, 64x64 each)
// LDS: As[128][520] bf16 (133120) + Bs[4][256][8] bf16 (16384) + c2s[1024] f32 (4096)
//      + red (128*4*3*4 = 6144)  => 159744 B  (<= 160 KiB, 1 block/CU)
#define SMEM_MAIN 159744

__global__ __launch_bounds__(512, 2) void vq_main(const float* __restrict__ x,
                                                  const int4* __restrict__ cbp4,
                                                  const float* __restrict__ c2h,
                                                  int* __restrict__ idx,
                                                  int* __restrict__ list,
                                                  int* __restrict__ counter) {
  extern __shared__ char smem[];
  unsigned short* As = (unsigned short*)smem;                       // [128][520] (+8 pad: conflict-free)
  unsigned short* Bs = (unsigned short*)(smem + 133120);            // [kg 0..3][n 0..255][8]
  float* c2s  = (float*)(smem + 133120 + 16384);                    // [1024]
  float* red1 = (float*)(smem + 133120 + 16384 + 4096);             // [128][4]
  float* red2 = red1 + 512;
  int*   redc = (int*)(red2 + 512);

  const int tid = threadIdx.x;
  const int lane = tid & 63;
  const int wv = tid >> 6;
  const int mw = wv & 1, nw = wv >> 1;
  const int c = lane & 15, q = lane >> 4;
  const int mblock = blockIdx.x;

  // ---- A: fp32 -> bf16 into padded LDS (read x exactly once from HBM)
  {
    const float4* xv = (const float4*)(x + (size_t)mblock * 128 * KDIM);
#pragma unroll
    for (int r = 0; r < 16; ++r) {
      int g = r * 512 + tid;
      int m = g >> 6, kg = g & 63;                     // wave-uniform m, lane-varying kg
      float4 u = xv[(size_t)m * 128 + kg * 2];
      float4 v = xv[(size_t)m * 128 + kg * 2 + 1];
      unsigned r0 = f2bf(u.x) | ((unsigned)f2bf(u.y) << 16);
      unsigned r1 = f2bf(u.z) | ((unsigned)f2bf(u.w) << 16);
      unsigned r2 = f2bf(v.x) | ((unsigned)f2bf(v.y) << 16);
      unsigned r3 = f2bf(v.z) | ((unsigned)f2bf(v.w) << 16);
      *(int4*)(As + (size_t)m * 520 + kg * 8) = make_int4((int)r0, (int)r1, (int)r2, (int)r3);
    }
    c2s[tid] = c2h[tid];
    c2s[tid + 512] = c2h[tid + 512];
  }

  // register-double-buffered B prefetch (distance 2); chunk = 16KB = 1024 int4
  int4 pf[2][2];
  pf[0][0] = cbp4[tid];          pf[0][1] = cbp4[512 + tid];
  pf[1][0] = cbp4[1024 + tid];   pf[1][1] = cbp4[1536 + tid];

  float mn1[4][4], mn2[4][4];
  int mcol[4][4];
#pragma unroll
  for (int i = 0; i < 4; ++i)
#pragma unroll
    for (int r = 0; r < 4; ++r) { mn1[i][r] = 1e30f; mn2[i][r] = 1e30f; mcol[i][r] = 0; }

  const int aBase = (mw * 64 + c) * 520 + q * 8;       // elems
  const int bBase = (q * 256 + nw * 64 + c) * 8;       // elems

  for (int no = 0; no < 4; ++no) {
    f32x4 acc[4][4];
#pragma unroll
    for (int i = 0; i < 4; ++i)
#pragma unroll
      for (int j = 0; j < 4; ++j) acc[i][j] = (f32x4){0.f, 0.f, 0.f, 0.f};

    for (int ki = 0; ki < 16; ++ki) {
      const int cid = no * 16 + ki;
      const int s = cid & 1;
      __syncthreads();                                  // prior frag reads done
      ((int4*)Bs)[tid] = pf[s][0];
      ((int4*)Bs)[512 + tid] = pf[s][1];
      if (cid + 2 < 64) {                               // prefetch 2 ahead
        pf[s][0] = cbp4[(size_t)(cid + 2) * 1024 + tid];
        pf[s][1] = cbp4[(size_t)(cid + 2) * 1024 + 512 + tid];
      }
      __syncthreads();                                  // Bs ready
      short8 a[4], b[4];
#pragma unroll
      for (int t = 0; t < 4; ++t)
        a[t] = *(const short8*)(As + aBase + t * (16 * 520) + ki * 32);
#pragma unroll
      for (int t = 0; t < 4; ++t)
        b[t] = *(const short8*)(Bs + bBase + t * (16 * 8));
#pragma unroll
      for (int i = 0; i < 4; ++i)
#pragma unroll
        for (int j = 0; j < 4; ++j)
          acc[i][j] = __builtin_amdgcn_mfma_f32_16x16x32_bf16(a[i], b[j], acc[i][j], 0, 0, 0);
    }

    // fused argmin update: s = 0.5*c2 - dot ; track (min1, min2, col)
#pragma unroll
    for (int j = 0; j < 4; ++j) {
      int colb = no * 256 + nw * 64 + j * 16 + c;
      float c2v = c2s[colb];
#pragma unroll
      for (int i = 0; i < 4; ++i)
#pragma unroll
        for (int r = 0; r < 4; ++r) {
          float sv = c2v - acc[i][j][r];
          float hi = fmaxf(sv, mn1[i][r]);
          mn2[i][r] = fminf(mn2[i][r], hi);
          bool lt = sv < mn1[i][r];
          mn1[i][r] = lt ? sv : mn1[i][r];
          mcol[i][r] = lt ? colb : mcol[i][r];
        }
    }
  }

  // butterfly merge across the 16 col-lanes of each quad
#pragma unroll
  for (int m = 1; m < 16; m <<= 1) {
#pragma unroll
    for (int i = 0; i < 4; ++i)
#pragma unroll
      for (int r = 0; r < 4; ++r) {
        float o1 = __shfl_xor(mn1[i][r], m);
        float o2 = __shfl_xor(mn2[i][r], m);
        int   oc = __shfl_xor(mcol[i][r], m);
        float hi = fmaxf(o1, mn1[i][r]);
        mn2[i][r] = fminf(fminf(mn2[i][r], o2), hi);
        bool lt = o1 < mn1[i][r];
        mn1[i][r] = lt ? o1 : mn1[i][r];
        mcol[i][r] = lt ? oc : mcol[i][r];
      }
  }
  __syncthreads();
  if (c == 0) {
#pragma unroll
    for (int i = 0; i < 4; ++i)
#pragma unroll
      for (int r = 0; r < 4; ++r) {
        int rb = mw * 64 + i * 16 + q * 4 + r;          // C/D row = q*4+reg
        red1[rb * 4 + nw] = mn1[i][r];
        red2[rb * 4 + nw] = mn2[i][r];
        redc[rb * 4 + nw] = mcol[i][r];
      }
  }
  __syncthreads();
  if (tid < 128) {
    float b1 = red1[tid * 4], b2 = red2[tid * 4];
    int bc = redc[tid * 4];
#pragma unroll
    for (int w = 1; w < 4; ++w) {
      float o1 = red1[tid * 4 + w], o2 = red2[tid * 4 + w];
      int oc = redc[tid * 4 + w];
      float hi = fmaxf(o1, b1);
      b2 = fminf(fminf(b2, o2), hi);
      if (o1 < b1) { b1 = o1; bc = oc; }
    }
    int qg = mblock * 128 + tid;
    idx[qg] = bc;
    if (b2 - b1 < TAU_S) { int p = atomicAdd(counter, 1); list[p] = qg; }
  }
}

// ---------------- refine: exact re-scan of flagged queries (4 per block) ----------------
__global__ __launch_bounds__(256) void vq_refine(const float* __restrict__ x,
                                                 const float* __restrict__ cb,
                                                 const double* __restrict__ c2d,
                                                 const int* __restrict__ list,
                                                 const int* __restrict__ counter,
                                                 int* __restrict__ idx) {
  __shared__ float xs[4][KDIM];
  __shared__ double rv[4][4];
  __shared__ int rc[4][4];
  const int cnt = counter[0];
  const int tid = threadIdx.x, lane = tid & 63, wv = tid >> 6;
  const float4* cb4 = (const float4*)cb;
  for (int g = blockIdx.x; g * 4 < cnt; g += gridDim.x) {
    int qn = min(4, cnt - g * 4);
    __syncthreads();
#pragma unroll
    for (int j = 0; j < 4; ++j) {
      int qq = list[g * 4 + (j < qn ? j : 0)];
      xs[j][tid] = x[(size_t)qq * KDIM + tid];
      xs[j][tid + 256] = x[(size_t)qq * KDIM + tid + 256];
    }
    __syncthreads();
    float a0[4][4], a1[4][4];
#pragma unroll
    for (int jj = 0; jj < 4; ++jj)
#pragma unroll
      for (int j = 0; j < 4; ++j) { a0[jj][j] = 0.f; a1[jj][j] = 0.f; }
    for (int k4 = 0; k4 < 128; k4 += 2) {
      float4 xv0[4], xv1[4];
#pragma unroll
      for (int j = 0; j < 4; ++j) {
        xv0[j] = *(const float4*)&xs[j][k4 * 4];
        xv1[j] = *(const float4*)&xs[j][k4 * 4 + 4];
      }
#pragma unroll
      for (int jj = 0; jj < 4; ++jj) {
        float4 cv0 = cb4[(size_t)(tid + jj * 256) * 128 + k4];
        float4 cv1 = cb4[(size_t)(tid + jj * 256) * 128 + k4 + 1];
#pragma unroll
        for (int j = 0; j < 4; ++j) {
          a0[jj][j] = fmaf(cv0.x, xv0[j].x, a0[jj][j]);
          a0[jj][j] = fmaf(cv0.y, xv0[j].y, a0[jj][j]);
          a0[jj][j] = fmaf(cv0.z, xv0[j].z, a0[jj][j]);
          a0[jj][j] = fmaf(cv0.w, xv0[j].w, a0[jj][j]);
          a1[jj][j] = fmaf(cv1.x, xv1[j].x, a1[jj][j]);
          a1[jj][j] = fmaf(cv1.y, xv1[j].y, a1[jj][j]);
          a1[jj][j] = fmaf(cv1.z, xv1[j].z, a1[jj][j]);
          a1[jj][j] = fmaf(cv1.w, xv1[j].w, a1[jj][j]);
        }
      }
    }
    double best[4]; int bcol[4];
#pragma unroll
    for (int j = 0; j < 4; ++j) { best[j] = 1e300; bcol[j] = 0; }
#pragma unroll
    for (int jj = 0; jj < 4; ++jj) {
      int code = tid + jj * 256;
      double base = c2d[code];
#pragma unroll
      for (int j = 0; j < 4; ++j) {
        double s = base - ((double)a0[jj][j] + (double)a1[jj][j]);
        if (s < best[j]) { best[j] = s; bcol[j] = code; }
      }
    }
#pragma unroll
    for (int m = 1; m < 64; m <<= 1)
#pragma unroll
      for (int j = 0; j < 4; ++j) {
        double o = __shfl_xor(best[j], m);
        int oc = __shfl_xor(bcol[j], m);
        if (o < best[j]) { best[j] = o; bcol[j] = oc; }
      }
    if (lane == 0)
#pragma unroll
      for (int j = 0; j < 4; ++j) { rv[wv][j] = best[j]; rc[wv][j] = bcol[j]; }
    __syncthreads();
    if (tid < qn) {
      double b = rv[0][tid]; int bc = rc[0][tid];
#pragma unroll
      for (int w = 1; w < 4; ++w)
        if (rv[w][tid] < b) { b = rv[w][tid]; bc = rc[w][tid]; }
      idx[list[g * 4 + tid]] = bc;
    }
  }
}

// ---------------- gather: out[q] = codebook[idx[q]] ----------------
__global__ __launch_bounds__(256) void vq_gather(const float* __restrict__ cb,
                                                 const int* __restrict__ idx,
                                                 float* __restrict__ out) {
  size_t i = (size_t)blockIdx.x * 256 + threadIdx.x;   // float4 index
  int qg = (int)(i >> 7), d = (int)(i & 127);
  ((float4*)out)[i] = ((const float4*)cb)[(size_t)idx[qg] * 128 + d];
}

extern "C" void kernel_launch(void* const* d_in, const int* in_sizes, int n_in,
                              void* d_out, int out_size, void* d_ws, size_t ws_size,
                              hipStream_t stream) {
  const float* x = (const float*)d_in[0];
  const float* cb = (const float*)d_in[1];
  float* out = (float*)d_out;
  char* ws = (char*)d_ws;
  if (ws_size < (size_t)(WS_CTR + 4)) {
    fprintf(stderr, "vq: ws_size %zu too small (need %d)\n", ws_size, WS_CTR + 4);
  }
  unsigned short* cbp = (unsigned short*)(ws + WS_CBP);
  float* c2h = (float*)(ws + WS_C2H);
  double* c2d = (double*)(ws + WS_C2D);
  int* idx = (int*)(ws + WS_IDX);
  int* list = (int*)(ws + WS_LIST);
  int* counter = (int*)(ws + WS_CTR);

  hipMemsetAsync(counter, 0, 4, stream);
  vq_prep<<<256, 256, 0, stream>>>(cb, cbp, c2h, c2d);
  (void)hipFuncSetAttribute(reinterpret_cast<const void*>(&vq_main),
                            hipFuncAttributeMaxDynamicSharedMemorySize, SMEM_MAIN);
  vq_main<<<512, 512, SMEM_MAIN, stream>>>(x, (const int4*)cbp, c2h, idx, list, counter);
  vq_refine<<<512, 256, 0, stream>>>(x, cb, c2d, list, counter, idx);
  vq_gather<<<32768, 256, 0, stream>>>(cb, idx, out);
}